// Round 3
// baseline (478.290 us; speedup 1.0000x reference)
//
#include <hip/hip_runtime.h>
#include <stdint.h>

typedef __attribute__((ext_vector_type(8))) __bf16 bf16x8;
typedef __attribute__((ext_vector_type(4))) float f32x4;
typedef __attribute__((ext_vector_type(8))) unsigned short ushort8;
typedef __attribute__((ext_vector_type(4))) unsigned short ushort4v;
typedef unsigned short u16;
typedef unsigned int u32;

__device__ __forceinline__ u16 f2bf(float f) {
    __bf16 h = (__bf16)f;
    return __builtin_bit_cast(u16, h);
}

__device__ __forceinline__ f32x4 mfma16(bf16x8 a, bf16x8 b, f32x4 c) {
    return __builtin_amdgcn_mfma_f32_16x16x32_bf16(a, b, c, 0, 0, 0);
}

// ---------------------------------------------------------------------------
// Weight prep: WT[j][k] = W_sel[k][j%256] as bf16 (j<256:Wq, <512:Wk, <768:Wv)
//              WOT[o][h] = Wo[h][o] as bf16
// ---------------------------------------------------------------------------
__global__ __launch_bounds__(256) void prep_w(
    const float* __restrict__ Wq, const float* __restrict__ Wk,
    const float* __restrict__ Wv, const float* __restrict__ Wo,
    u16* __restrict__ WT, u16* __restrict__ WOT)
{
    int idx = blockIdx.x * 256 + threadIdx.x;  // 0..262143
    if (idx < 196608) {
        int j = idx >> 8, k = idx & 255;
        const float* W = (j < 256) ? Wq : (j < 512) ? Wk : Wv;
        WT[idx] = f2bf(W[k * 256 + (j & 255)]);
    } else {
        int t = idx - 196608;
        int j = t >> 8, k = t & 255;
        WOT[t] = f2bf(Wo[k * 256 + j]);
    }
}

// ---------------------------------------------------------------------------
// QKV projection: C[65536,768] = relu(X[65536,256] @ W + b), bf16 out.
// ---------------------------------------------------------------------------
__global__ __launch_bounds__(256, 2) void qkv_gemm(
    const float* __restrict__ X, const u16* __restrict__ WT,
    const float* __restrict__ bQ, const float* __restrict__ bK,
    const float* __restrict__ bV,
    u16* __restrict__ outQ, u16* __restrict__ outK, u16* __restrict__ outVT)
{
    __shared__ __align__(16) u16 As[128 * 256];  // 64KB, XOR-swizzled rows
    __shared__ __align__(16) u16 Bs[128 * 64];   // 16KB, XOR-swizzled rows
    const int tid = threadIdx.x;
    const int m0 = blockIdx.x * 128;

    #pragma unroll
    for (int i = 0; i < 32; ++i) {
        int flat = (i * 256 + tid) * 4;
        int r = flat >> 8, c = flat & 255;
        const float4 f = *reinterpret_cast<const float4*>(X + (size_t)(m0 + r) * 256 + c);
        ushort4v h;
        h.x = f2bf(f.x); h.y = f2bf(f.y); h.z = f2bf(f.z); h.w = f2bf(f.w);
        int byte = (r * 512 + c * 2) ^ ((r & 7) << 4);
        *reinterpret_cast<ushort4v*>(reinterpret_cast<char*>(As) + byte) = h;
    }

    const int lane = tid & 63, wid = tid >> 6;
    const int wr = wid >> 1, wc = wid & 1;
    const int lr = lane & 15, lg = lane >> 4;

    for (int cb = 0; cb < 6; ++cb) {
        const int jbase = cb * 128;
        f32x4 acc[4][4];
        #pragma unroll
        for (int a = 0; a < 4; ++a)
            #pragma unroll
            for (int b = 0; b < 4; ++b) acc[a][b] = (f32x4){0.f, 0.f, 0.f, 0.f};

        for (int kk = 0; kk < 256; kk += 64) {
            __syncthreads();
            #pragma unroll
            for (int i = 0; i < 4; ++i) {
                int e = (i * 256 + tid) * 8;
                int r = e >> 6, c = e & 63;
                ushort8 d = *reinterpret_cast<const ushort8*>(WT + (size_t)(jbase + r) * 256 + kk + c);
                int byte = (r * 128 + c * 2) ^ ((r & 7) << 4);
                *reinterpret_cast<ushort8*>(reinterpret_cast<char*>(Bs) + byte) = d;
            }
            __syncthreads();
            #pragma unroll
            for (int ks = 0; ks < 2; ++ks) {
                bf16x8 af[4], bfr[4];
                #pragma unroll
                for (int mt = 0; mt < 4; ++mt) {
                    int r = wr * 64 + mt * 16 + lr;
                    int byte = (r * 512 + (kk + ks * 32 + lg * 8) * 2) ^ ((r & 7) << 4);
                    af[mt] = *reinterpret_cast<const bf16x8*>(reinterpret_cast<const char*>(As) + byte);
                }
                #pragma unroll
                for (int nt = 0; nt < 4; ++nt) {
                    int r = wc * 64 + nt * 16 + lr;
                    int byte = (r * 128 + (ks * 32 + lg * 8) * 2) ^ ((r & 7) << 4);
                    bfr[nt] = *reinterpret_cast<const bf16x8*>(reinterpret_cast<const char*>(Bs) + byte);
                }
                #pragma unroll
                for (int mt = 0; mt < 4; ++mt)
                    #pragma unroll
                    for (int nt = 0; nt < 4; ++nt)
                        acc[mt][nt] = mfma16(af[mt], bfr[nt], acc[mt][nt]);
            }
        }
        const float* bias = (cb < 2) ? bQ : (cb < 4) ? bK : bV;
        float bcol[4];
        #pragma unroll
        for (int nt = 0; nt < 4; ++nt)
            bcol[nt] = bias[(jbase + wc * 64 + nt * 16 + lr) & 255];
        #pragma unroll
        for (int mt = 0; mt < 4; ++mt) {
            #pragma unroll
            for (int nt = 0; nt < 4; ++nt) {
                #pragma unroll
                for (int j = 0; j < 4; ++j) {
                    float v = fmaxf(acc[mt][nt][j] + bcol[nt], 0.f);
                    u16 h = f2bf(v);
                    int row = m0 + wr * 64 + mt * 16 + lg * 4 + j;
                    int col = jbase + wc * 64 + nt * 16 + lr;
                    if (cb < 2) {
                        outQ[(size_t)row * 256 + col] = h;
                    } else if (cb < 4) {
                        outK[(size_t)row * 256 + (col - 256)] = h;
                    } else {
                        int bb = row >> 9, n = row & 511;
                        outVT[(size_t)bb * 131072 + (size_t)(col - 512) * 512 + n] = h;
                    }
                }
            }
        }
    }
}

// ---------------------------------------------------------------------------
// Flash attention, barrier-free, occupancy-tuned:
//  - __launch_bounds__(256,4): VGPR <= 128 -> 4 blocks/CU, grid fully resident
//  - Q fragments reloaded per kt (L1-hot) instead of 32 persistent VGPRs
//  - mask prefetched 1 tile ahead as 4x float4/lane, packed to 16 bits,
//    redistributed with 4 shuffles (mask is binary: p = bit ? s : -9e15)
//  - defer-rescale (T13): skip acc rescale when running max doesn't grow
// ---------------------------------------------------------------------------
__global__ __launch_bounds__(256, 4) void attn_kernel(
    const u16* __restrict__ Q, const u16* __restrict__ K,
    const u16* __restrict__ VT, const float* __restrict__ Mask,
    u16* __restrict__ Out)
{
    __shared__ __align__(16) u16 p_lds[4][16 * 64]; // 8KB total, per-wave
    const int tid = threadIdx.x;
    const int b  = blockIdx.x & 127;   // batch; same XCD for all rb of a batch
    const int rb = blockIdx.x >> 7;
    const int lane = tid & 63, wid = tid >> 6;
    const int lr = lane & 15, lg = lane >> 4;
    const int la3 = lane & 3;
    const int n0 = rb * 64 + wid * 16;
    const u16* qbat = Q  + (size_t)b * 512 * 256;
    const u16* kbat = K  + (size_t)b * 512 * 256;
    const u16* vbat = VT + (size_t)b * 256 * 512;
    // mask rows n0+lg*4+j, 4 consecutive keys per lane starting at lr*4
    const float* mbat = Mask + ((size_t)b * 512 + n0 + lg * 4) * 512;

    // prefetch mask tile kt=0: mf[j] = keys [lr*4, lr*4+4) of row lg*4+j
    f32x4 mf[4];
    #pragma unroll
    for (int j = 0; j < 4; ++j)
        mf[j] = __builtin_nontemporal_load(
            reinterpret_cast<const f32x4*>(mbat + (size_t)j * 512 + lr * 4));

    f32x4 acc[16];
    #pragma unroll
    for (int i = 0; i < 16; ++i) acc[i] = (f32x4){0.f, 0.f, 0.f, 0.f};
    float mreg[4], lreg[4];
    #pragma unroll
    for (int j = 0; j < 4; ++j) { mreg[j] = -__builtin_inff(); lreg[j] = 0.f; }

    for (int kt = 0; kt < 8; ++kt) {
        // ---- pack current mask tile: bit (j*4+c) = mask(row j, key lr*4+c) ----
        u32 nmP = 0;
        #pragma unroll
        for (int j = 0; j < 4; ++j) {
            #pragma unroll
            for (int c = 0; c < 4; ++c)
                nmP |= (mf[j][c] > 0.5f ? 1u : 0u) << (j * 4 + c);
        }

        // ---- S = Q K^T : 16 rows x 64 keys, operands straight from global ----
        f32x4 s[4];
        #pragma unroll
        for (int ct = 0; ct < 4; ++ct) s[ct] = (f32x4){0.f, 0.f, 0.f, 0.f};
        __builtin_amdgcn_s_setprio(1);
        #pragma unroll
        for (int ks = 0; ks < 8; ++ks) {
            bf16x8 qv = *reinterpret_cast<const bf16x8*>(
                qbat + (size_t)(n0 + lr) * 256 + ks * 32 + lg * 8);
            #pragma unroll
            for (int ct = 0; ct < 4; ++ct) {
                bf16x8 kf = *reinterpret_cast<const bf16x8*>(
                    kbat + (size_t)(kt * 64 + ct * 16 + lr) * 256 + ks * 32 + lg * 8);
                s[ct] = mfma16(qv, kf, s[ct]);
            }
        }
        __builtin_amdgcn_s_setprio(0);

        // ---- issue next mask tile loads (latency hides under softmax+PV+QK) ----
        if (kt < 7) {
            #pragma unroll
            for (int j = 0; j < 4; ++j)
                mf[j] = __builtin_nontemporal_load(reinterpret_cast<const f32x4*>(
                    mbat + (size_t)j * 512 + (kt + 1) * 64 + lr * 4));
        }

        // ---- redistribute mask bits + select ----
        // bit for (row j, key ct*16+lr) lives in lane lg*16 + ct*4 + (lr>>2),
        // position j*4 + (lr&3)
        float p[4][4];
        #pragma unroll
        for (int ct = 0; ct < 4; ++ct) {
            u32 wct = __shfl(nmP, (lane & 48) + ct * 4 + ((lane >> 2) & 3));
            #pragma unroll
            for (int j = 0; j < 4; ++j) {
                u32 bit = (wct >> (j * 4)) >> la3;
                p[ct][j] = (bit & 1u) ? s[ct][j] : -9.0e15f;
            }
        }

        // ---- online softmax with defer-rescale ----
        float r0j[4];
        bool need = false;
        #pragma unroll
        for (int j = 0; j < 4; ++j) {
            float r0 = fmaxf(fmaxf(p[0][j], p[1][j]), fmaxf(p[2][j], p[3][j]));
            r0 = fmaxf(r0, __shfl_xor(r0, 1));
            r0 = fmaxf(r0, __shfl_xor(r0, 2));
            r0 = fmaxf(r0, __shfl_xor(r0, 4));
            r0 = fmaxf(r0, __shfl_xor(r0, 8));
            r0j[j] = r0;
            need = need || (r0 > mreg[j]);
        }
        if (__any(need)) {
            #pragma unroll
            for (int j = 0; j < 4; ++j) {
                float mnew = fmaxf(mreg[j], r0j[j]);
                float sc = __expf(mreg[j] - mnew);
                mreg[j] = mnew;
                lreg[j] *= sc;
                #pragma unroll
                for (int ht = 0; ht < 16; ++ht) acc[ht][j] *= sc;
            }
        }
        #pragma unroll
        for (int j = 0; j < 4; ++j) {
            float ps = 0.f;
            #pragma unroll
            for (int ct = 0; ct < 4; ++ct) {
                float e = __expf(p[ct][j] - mreg[j]);
                p[ct][j] = e;
                ps += e;
            }
            lreg[j] += ps;
        }

        // ---- P (D-layout) -> per-wave LDS -> A-fragment layout ----
        #pragma unroll
        for (int ct = 0; ct < 4; ++ct) {
            #pragma unroll
            for (int j = 0; j < 4; ++j) {
                int pr = lg * 4 + j, pc = ct * 16 + lr;
                int byte = (pr * 128 + pc * 2) ^ ((pr & 7) << 4);
                *reinterpret_cast<u16*>(reinterpret_cast<char*>(p_lds[wid]) + byte) = f2bf(p[ct][j]);
            }
        }
        // ---- PV: acc[16 rows][256 h] += P[16][64] @ V[64][256] ----
        #pragma unroll
        for (int ks2 = 0; ks2 < 2; ++ks2) {
            int byteA = (lr * 128 + (ks2 * 32 + lg * 8) * 2) ^ ((lr & 7) << 4);
            bf16x8 pf = *reinterpret_cast<const bf16x8*>(reinterpret_cast<const char*>(p_lds[wid]) + byteA);
            __builtin_amdgcn_s_setprio(1);
            #pragma unroll
            for (int ht = 0; ht < 16; ++ht) {
                bf16x8 vf = *reinterpret_cast<const bf16x8*>(
                    vbat + (size_t)(ht * 16 + lr) * 512 + kt * 64 + ks2 * 32 + lg * 8);
                acc[ht] = mfma16(pf, vf, acc[ht]);
            }
            __builtin_amdgcn_s_setprio(0);
        }
    }

    // finalize: normalize and store bf16
    #pragma unroll
    for (int j = 0; j < 4; ++j) {
        float lt = lreg[j];
        lt += __shfl_xor(lt, 1);
        lt += __shfl_xor(lt, 2);
        lt += __shfl_xor(lt, 4);
        lt += __shfl_xor(lt, 8);
        float inv = 1.0f / lt;
        int qn = n0 + lg * 4 + j;
        u16* orow = Out + ((size_t)b * 512 + qn) * 256;
        #pragma unroll
        for (int ht = 0; ht < 16; ++ht)
            orow[ht * 16 + lr] = f2bf(acc[ht][j] * inv);
    }
}

// ---------------------------------------------------------------------------
// Output projection: Out[65536,256] = relu(A[65536,256](bf16) @ Wo + bo), f32.
// ---------------------------------------------------------------------------
__global__ __launch_bounds__(256, 2) void out_gemm(
    const u16* __restrict__ A, const u16* __restrict__ WOT,
    const float* __restrict__ bO, float* __restrict__ Out)
{
    __shared__ __align__(16) u16 As[128 * 256];
    __shared__ __align__(16) u16 Bs[128 * 64];
    const int tid = threadIdx.x;
    const int m0 = blockIdx.x * 128;

    #pragma unroll
    for (int i = 0; i < 16; ++i) {
        int e = (i * 256 + tid) * 8;
        int r = e >> 8, c = e & 255;
        ushort8 d = *reinterpret_cast<const ushort8*>(A + (size_t)(m0 + r) * 256 + c);
        int byte = (r * 512 + c * 2) ^ ((r & 7) << 4);
        *reinterpret_cast<ushort8*>(reinterpret_cast<char*>(As) + byte) = d;
    }

    const int lane = tid & 63, wid = tid >> 6;
    const int wr = wid >> 1, wc = wid & 1;
    const int lr = lane & 15, lg = lane >> 4;

    for (int cb = 0; cb < 2; ++cb) {
        const int jbase = cb * 128;
        f32x4 acc[4][4];
        #pragma unroll
        for (int a = 0; a < 4; ++a)
            #pragma unroll
            for (int b = 0; b < 4; ++b) acc[a][b] = (f32x4){0.f, 0.f, 0.f, 0.f};

        for (int kk = 0; kk < 256; kk += 64) {
            __syncthreads();
            #pragma unroll
            for (int i = 0; i < 4; ++i) {
                int e = (i * 256 + tid) * 8;
                int r = e >> 6, c = e & 63;
                ushort8 d = *reinterpret_cast<const ushort8*>(WOT + (size_t)(jbase + r) * 256 + kk + c);
                int byte = (r * 128 + c * 2) ^ ((r & 7) << 4);
                *reinterpret_cast<ushort8*>(reinterpret_cast<char*>(Bs) + byte) = d;
            }
            __syncthreads();
            #pragma unroll
            for (int ks = 0; ks < 2; ++ks) {
                bf16x8 af[4], bfr[4];
                #pragma unroll
                for (int mt = 0; mt < 4; ++mt) {
                    int r = wr * 64 + mt * 16 + lr;
                    int byte = (r * 512 + (kk + ks * 32 + lg * 8) * 2) ^ ((r & 7) << 4);
                    af[mt] = *reinterpret_cast<const bf16x8*>(reinterpret_cast<const char*>(As) + byte);
                }
                #pragma unroll
                for (int nt = 0; nt < 4; ++nt) {
                    int r = wc * 64 + nt * 16 + lr;
                    int byte = (r * 128 + (ks * 32 + lg * 8) * 2) ^ ((r & 7) << 4);
                    bfr[nt] = *reinterpret_cast<const bf16x8*>(reinterpret_cast<const char*>(Bs) + byte);
                }
                #pragma unroll
                for (int mt = 0; mt < 4; ++mt)
                    #pragma unroll
                    for (int nt = 0; nt < 4; ++nt)
                        acc[mt][nt] = mfma16(af[mt], bfr[nt], acc[mt][nt]);
            }
        }
        float bcol[4];
        #pragma unroll
        for (int nt = 0; nt < 4; ++nt)
            bcol[nt] = bO[jbase + wc * 64 + nt * 16 + lr];
        #pragma unroll
        for (int mt = 0; mt < 4; ++mt) {
            #pragma unroll
            for (int nt = 0; nt < 4; ++nt) {
                #pragma unroll
                for (int j = 0; j < 4; ++j) {
                    float v = fmaxf(acc[mt][nt][j] + bcol[nt], 0.f);
                    int row = m0 + wr * 64 + mt * 16 + lg * 4 + j;
                    int col = jbase + wc * 64 + nt * 16 + lr;
                    Out[(size_t)row * 256 + col] = v;
                }
            }
        }
    }
}

// ---------------------------------------------------------------------------
extern "C" void kernel_launch(void* const* d_in, const int* in_sizes, int n_in,
                              void* d_out, int out_size, void* d_ws, size_t ws_size,
                              hipStream_t stream) {
    const float* x    = (const float*)d_in[0];
    const float* mask = (const float*)d_in[1];
    const float* Wv   = (const float*)d_in[2];
    const float* bv   = (const float*)d_in[3];
    const float* Wk   = (const float*)d_in[4];
    const float* bk   = (const float*)d_in[5];
    const float* Wq   = (const float*)d_in[6];
    const float* bq   = (const float*)d_in[7];
    const float* Wo   = (const float*)d_in[8];
    const float* bo   = (const float*)d_in[9];
    float* out = (float*)d_out;

    char* ws = (char*)d_ws;
    u16* WT  = (u16*)(ws);                          // 768*256 bf16 = 384KB
    u16* WOT = (u16*)(ws + 393216);                 // 256*256 bf16 = 128KB
    u16* Qb  = (u16*)(ws + 524288);                 // 33.55MB (also attn out)
    u16* Kb  = (u16*)(ws + 524288 + 33554432);      // 33.55MB
    u16* VTb = (u16*)(ws + 524288 + 2 * 33554432);  // 33.55MB, [b][h][n]

    prep_w<<<1024, 256, 0, stream>>>(Wq, Wk, Wv, Wo, WT, WOT);
    qkv_gemm<<<512, 256, 0, stream>>>(x, WT, bq, bk, bv, Qb, Kb, VTb);
    attn_kernel<<<1024, 256, 0, stream>>>(Qb, Kb, VTb, mask, Qb);
    out_gemm<<<512, 256, 0, stream>>>(Qb, WOT, bo, out);
}

// Round 4
// 198.497 us; speedup vs baseline: 2.4096x; 2.4096x over previous
//
#include <hip/hip_runtime.h>
#include <stdint.h>

typedef __attribute__((ext_vector_type(8))) __bf16 bf16x8;
typedef __attribute__((ext_vector_type(4))) float f32x4;
typedef __attribute__((ext_vector_type(8))) unsigned short ushort8;
typedef __attribute__((ext_vector_type(4))) unsigned short ushort4v;
typedef unsigned short u16;
typedef unsigned int u32;

__device__ __forceinline__ u16 f2bf(float f) {
    __bf16 h = (__bf16)f;
    return __builtin_bit_cast(u16, h);
}

__device__ __forceinline__ f32x4 mfma16(bf16x8 a, bf16x8 b, f32x4 c) {
    return __builtin_amdgcn_mfma_f32_16x16x32_bf16(a, b, c, 0, 0, 0);
}

typedef __attribute__((address_space(1))) const char g_char;
typedef __attribute__((address_space(3))) char l_char;
__device__ __forceinline__ void gload_lds16(const void* g, void* l) {
    // async 16B/lane global->LDS; LDS dest = wave-uniform base + lane*16
    __builtin_amdgcn_global_load_lds((g_char*)g, (l_char*)l, 16, 0, 0);
}

// ---------------------------------------------------------------------------
// Weight prep: WT[j][k] = W_sel[k][j%256] as bf16 (j<256:Wq, <512:Wk, <768:Wv)
//              WOT[o][h] = Wo[h][o] as bf16
// ---------------------------------------------------------------------------
__global__ __launch_bounds__(256) void prep_w(
    const float* __restrict__ Wq, const float* __restrict__ Wk,
    const float* __restrict__ Wv, const float* __restrict__ Wo,
    u16* __restrict__ WT, u16* __restrict__ WOT)
{
    int idx = blockIdx.x * 256 + threadIdx.x;  // 0..262143
    if (idx < 196608) {
        int j = idx >> 8, k = idx & 255;
        const float* W = (j < 256) ? Wq : (j < 512) ? Wk : Wv;
        WT[idx] = f2bf(W[k * 256 + (j & 255)]);
    } else {
        int t = idx - 196608;
        int j = t >> 8, k = t & 255;
        WOT[t] = f2bf(Wo[k * 256 + j]);
    }
}

// ---------------------------------------------------------------------------
// QKV projection: C[65536,768] = relu(X[65536,256] @ W + b), bf16 out.
// ---------------------------------------------------------------------------
__global__ __launch_bounds__(256, 2) void qkv_gemm(
    const float* __restrict__ X, const u16* __restrict__ WT,
    const float* __restrict__ bQ, const float* __restrict__ bK,
    const float* __restrict__ bV,
    u16* __restrict__ outQ, u16* __restrict__ outK, u16* __restrict__ outVT)
{
    __shared__ __align__(16) u16 As[128 * 256];  // 64KB, XOR-swizzled rows
    __shared__ __align__(16) u16 Bs[128 * 64];   // 16KB, XOR-swizzled rows
    const int tid = threadIdx.x;
    const int m0 = blockIdx.x * 128;

    #pragma unroll
    for (int i = 0; i < 32; ++i) {
        int flat = (i * 256 + tid) * 4;
        int r = flat >> 8, c = flat & 255;
        const float4 f = *reinterpret_cast<const float4*>(X + (size_t)(m0 + r) * 256 + c);
        ushort4v h;
        h.x = f2bf(f.x); h.y = f2bf(f.y); h.z = f2bf(f.z); h.w = f2bf(f.w);
        int byte = (r * 512 + c * 2) ^ ((r & 7) << 4);
        *reinterpret_cast<ushort4v*>(reinterpret_cast<char*>(As) + byte) = h;
    }

    const int lane = tid & 63, wid = tid >> 6;
    const int wr = wid >> 1, wc = wid & 1;
    const int lr = lane & 15, lg = lane >> 4;

    for (int cb = 0; cb < 6; ++cb) {
        const int jbase = cb * 128;
        f32x4 acc[4][4];
        #pragma unroll
        for (int a = 0; a < 4; ++a)
            #pragma unroll
            for (int b = 0; b < 4; ++b) acc[a][b] = (f32x4){0.f, 0.f, 0.f, 0.f};

        for (int kk = 0; kk < 256; kk += 64) {
            __syncthreads();
            #pragma unroll
            for (int i = 0; i < 4; ++i) {
                int e = (i * 256 + tid) * 8;
                int r = e >> 6, c = e & 63;
                ushort8 d = *reinterpret_cast<const ushort8*>(WT + (size_t)(jbase + r) * 256 + kk + c);
                int byte = (r * 128 + c * 2) ^ ((r & 7) << 4);
                *reinterpret_cast<ushort8*>(reinterpret_cast<char*>(Bs) + byte) = d;
            }
            __syncthreads();
            #pragma unroll
            for (int ks = 0; ks < 2; ++ks) {
                bf16x8 af[4], bfr[4];
                #pragma unroll
                for (int mt = 0; mt < 4; ++mt) {
                    int r = wr * 64 + mt * 16 + lr;
                    int byte = (r * 512 + (kk + ks * 32 + lg * 8) * 2) ^ ((r & 7) << 4);
                    af[mt] = *reinterpret_cast<const bf16x8*>(reinterpret_cast<const char*>(As) + byte);
                }
                #pragma unroll
                for (int nt = 0; nt < 4; ++nt) {
                    int r = wc * 64 + nt * 16 + lr;
                    int byte = (r * 128 + (ks * 32 + lg * 8) * 2) ^ ((r & 7) << 4);
                    bfr[nt] = *reinterpret_cast<const bf16x8*>(reinterpret_cast<const char*>(Bs) + byte);
                }
                #pragma unroll
                for (int mt = 0; mt < 4; ++mt)
                    #pragma unroll
                    for (int nt = 0; nt < 4; ++nt)
                        acc[mt][nt] = mfma16(af[mt], bfr[nt], acc[mt][nt]);
            }
        }
        const float* bias = (cb < 2) ? bQ : (cb < 4) ? bK : bV;
        float bcol[4];
        #pragma unroll
        for (int nt = 0; nt < 4; ++nt)
            bcol[nt] = bias[(jbase + wc * 64 + nt * 16 + lr) & 255];
        #pragma unroll
        for (int mt = 0; mt < 4; ++mt) {
            #pragma unroll
            for (int nt = 0; nt < 4; ++nt) {
                #pragma unroll
                for (int j = 0; j < 4; ++j) {
                    float v = fmaxf(acc[mt][nt][j] + bcol[nt], 0.f);
                    u16 h = f2bf(v);
                    int row = m0 + wr * 64 + mt * 16 + lg * 4 + j;
                    int col = jbase + wc * 64 + nt * 16 + lr;
                    if (cb < 2) {
                        outQ[(size_t)row * 256 + col] = h;
                    } else if (cb < 4) {
                        outK[(size_t)row * 256 + (col - 256)] = h;
                    } else {
                        int bb = row >> 9, n = row & 511;
                        outVT[(size_t)bb * 131072 + (size_t)(col - 512) * 512 + n] = h;
                    }
                }
            }
        }
    }
}

// ---------------------------------------------------------------------------
// Flash attention r4: 512 threads (8 waves x 16 q-rows = 128 rows/block),
// KVBLK=32, K/V double-buffered in LDS via global_load_lds (16B, pre-swizzled
// global source for K so swizzled-LDS reads are conflict-free). One barrier
// per kt. 2 blocks/CU target (72KB LDS, VGPR<=128 natural).
// ---------------------------------------------------------------------------
__global__ __launch_bounds__(512) void attn_kernel(
    const u16* __restrict__ Q, const u16* __restrict__ K,
    const u16* __restrict__ VT, const float* __restrict__ Mask,
    u16* __restrict__ Out)
{
    __shared__ __align__(16) u16 k_lds[2][32 * 256];  // 2 x 16KB, XOR-swizzled rows
    __shared__ __align__(16) u16 v_lds[2][256 * 32];  // 2 x 16KB, linear [h][key]
    __shared__ __align__(16) u16 p_lds[8][16 * 32];   // 8KB, per-wave P
    const int tid = threadIdx.x;          // 0..511
    const int b  = blockIdx.x & 127;      // batch; blocks of batch b all == b mod 8 -> same XCD
    const int rb = blockIdx.x >> 7;       // 0..3
    const int lane = tid & 63, wid = tid >> 6;
    const int lr = lane & 15, lg = lane >> 4;
    const int n0 = rb * 128 + wid * 16;
    const u16* qbat = Q  + (size_t)b * 512 * 256;
    const u16* kbat = K  + (size_t)b * 512 * 256;
    const u16* vbat = VT + (size_t)b * 256 * 512;
    const float* mrow = Mask + ((size_t)b * 512 + n0 + lg * 4) * 512;

    // stage K[32][256] (swizzled via source) + V[256][32] (linear) into buf
    auto stage = [&](int buf, int kt) {
        #pragma unroll
        for (int i = 0; i < 2; ++i) {
            int p = (i * 512 + tid) * 16;
            // K: phys row = p>>9 (512B rows), col2 = p&511; src col2 ^= (row&7)<<4
            int krow = p >> 9, kcol2 = p & 511;
            int scol2 = kcol2 ^ ((krow & 7) << 4);
            const char* gk = reinterpret_cast<const char*>(kbat + (size_t)(kt * 32 + krow) * 256) + scol2;
            char* lk = reinterpret_cast<char*>(k_lds[buf]) + i * 8192 + wid * 1024;
            gload_lds16(gk, lk);
            // V: phys row = p>>6 (64B rows), col2 = p&63; linear
            int vrow = p >> 6, vcol2 = p & 63;
            const char* gv = reinterpret_cast<const char*>(vbat + (size_t)vrow * 512 + kt * 32) + vcol2;
            char* lv = reinterpret_cast<char*>(v_lds[buf]) + i * 8192 + wid * 1024;
            gload_lds16(gv, lv);
        }
    };

    // prologue: stage tile 0, load mask tile 0
    stage(0, 0);
    float mf[2][4];
    #pragma unroll
    for (int ct = 0; ct < 2; ++ct)
        #pragma unroll
        for (int j = 0; j < 4; ++j)
            mf[ct][j] = __builtin_nontemporal_load(mrow + (size_t)j * 512 + ct * 16 + lr);

    f32x4 acc[16];
    #pragma unroll
    for (int i = 0; i < 16; ++i) acc[i] = (f32x4){0.f, 0.f, 0.f, 0.f};
    float mreg[4], lreg[4];
    #pragma unroll
    for (int j = 0; j < 4; ++j) { mreg[j] = -__builtin_inff(); lreg[j] = 0.f; }

    __syncthreads();

    for (int kt = 0; kt < 16; ++kt) {
        const int cur = kt & 1;
        // issue next tile's staging (hides under this kt's compute)
        if (kt < 15) stage(cur ^ 1, kt + 1);

        // pack current mask bits, then reuse regs to prefetch next tile
        u32 mb = 0;
        #pragma unroll
        for (int ct = 0; ct < 2; ++ct)
            #pragma unroll
            for (int j = 0; j < 4; ++j)
                mb |= (mf[ct][j] > 0.5f ? 1u : 0u) << (ct * 4 + j);
        if (kt < 15) {
            #pragma unroll
            for (int ct = 0; ct < 2; ++ct)
                #pragma unroll
                for (int j = 0; j < 4; ++j)
                    mf[ct][j] = __builtin_nontemporal_load(
                        mrow + (size_t)j * 512 + (kt + 1) * 32 + ct * 16 + lr);
        }

        // ---- QK^T: 16 rows x 32 keys per wave ----
        f32x4 s[2];
        s[0] = (f32x4){0.f, 0.f, 0.f, 0.f};
        s[1] = (f32x4){0.f, 0.f, 0.f, 0.f};
        const char* kbase = reinterpret_cast<const char*>(k_lds[cur]);
        __builtin_amdgcn_s_setprio(1);
        #pragma unroll
        for (int ks = 0; ks < 8; ++ks) {
            bf16x8 qv = *reinterpret_cast<const bf16x8*>(
                qbat + (size_t)(n0 + lr) * 256 + ks * 32 + lg * 8);
            #pragma unroll
            for (int ct = 0; ct < 2; ++ct) {
                int krow = ct * 16 + lr;
                int byte = (krow * 512 + (ks * 32 + lg * 8) * 2) ^ ((krow & 7) << 4);
                bf16x8 kf = *reinterpret_cast<const bf16x8*>(kbase + byte);
                s[ct] = mfma16(qv, kf, s[ct]);
            }
        }
        __builtin_amdgcn_s_setprio(0);

        // ---- mask select + online softmax (defer-rescale) ----
        float p[2][4];
        #pragma unroll
        for (int ct = 0; ct < 2; ++ct)
            #pragma unroll
            for (int j = 0; j < 4; ++j)
                p[ct][j] = ((mb >> (ct * 4 + j)) & 1u) ? s[ct][j] : -9.0e15f;

        float r0j[4];
        bool need = false;
        #pragma unroll
        for (int j = 0; j < 4; ++j) {
            float r0 = fmaxf(p[0][j], p[1][j]);
            r0 = fmaxf(r0, __shfl_xor(r0, 1));
            r0 = fmaxf(r0, __shfl_xor(r0, 2));
            r0 = fmaxf(r0, __shfl_xor(r0, 4));
            r0 = fmaxf(r0, __shfl_xor(r0, 8));
            r0j[j] = r0;
            need = need || (r0 > mreg[j]);
        }
        if (__any(need)) {
            #pragma unroll
            for (int j = 0; j < 4; ++j) {
                float mnew = fmaxf(mreg[j], r0j[j]);
                float sc = __expf(mreg[j] - mnew);
                mreg[j] = mnew;
                lreg[j] *= sc;
                #pragma unroll
                for (int ht = 0; ht < 16; ++ht) acc[ht][j] *= sc;
            }
        }
        #pragma unroll
        for (int j = 0; j < 4; ++j) {
            float ps = 0.f;
            #pragma unroll
            for (int ct = 0; ct < 2; ++ct) {
                float e = __expf(p[ct][j] - mreg[j]);
                p[ct][j] = e;
                ps += e;
            }
            lreg[j] += ps;
        }

        // ---- P (D-layout) -> per-wave LDS [16 rows][32 keys], 64B rows ----
        #pragma unroll
        for (int ct = 0; ct < 2; ++ct)
            #pragma unroll
            for (int j = 0; j < 4; ++j) {
                int byte = (lg * 4 + j) * 64 + (ct * 16 + lr) * 2;
                *reinterpret_cast<u16*>(reinterpret_cast<char*>(p_lds[wid]) + byte) = f2bf(p[ct][j]);
            }

        // ---- PV: acc[16 rows][256 h] += P[16][32] @ V[32][256] ----
        bf16x8 pf = *reinterpret_cast<const bf16x8*>(
            reinterpret_cast<const char*>(p_lds[wid]) + lr * 64 + lg * 16);
        const char* vbase = reinterpret_cast<const char*>(v_lds[cur]);
        __builtin_amdgcn_s_setprio(1);
        #pragma unroll
        for (int ht = 0; ht < 16; ++ht) {
            bf16x8 vf = *reinterpret_cast<const bf16x8*>(vbase + (ht * 16 + lr) * 64 + lg * 16);
            acc[ht] = mfma16(pf, vf, acc[ht]);
        }
        __builtin_amdgcn_s_setprio(0);

        __syncthreads();  // drains vmcnt(0): next tile staged; LDS reads done
    }

    // finalize: normalize and store bf16
    #pragma unroll
    for (int j = 0; j < 4; ++j) {
        float lt = lreg[j];
        lt += __shfl_xor(lt, 1);
        lt += __shfl_xor(lt, 2);
        lt += __shfl_xor(lt, 4);
        lt += __shfl_xor(lt, 8);
        float inv = 1.0f / lt;
        int qn = n0 + lg * 4 + j;
        u16* orow = Out + ((size_t)b * 512 + qn) * 256;
        #pragma unroll
        for (int ht = 0; ht < 16; ++ht)
            orow[ht * 16 + lr] = f2bf(acc[ht][j] * inv);
    }
}

// ---------------------------------------------------------------------------
// Output projection: Out[65536,256] = relu(A[65536,256](bf16) @ Wo + bo), f32.
// ---------------------------------------------------------------------------
__global__ __launch_bounds__(256, 2) void out_gemm(
    const u16* __restrict__ A, const u16* __restrict__ WOT,
    const float* __restrict__ bO, float* __restrict__ Out)
{
    __shared__ __align__(16) u16 As[128 * 256];
    __shared__ __align__(16) u16 Bs[128 * 64];
    const int tid = threadIdx.x;
    const int m0 = blockIdx.x * 128;

    #pragma unroll
    for (int i = 0; i < 16; ++i) {
        int e = (i * 256 + tid) * 8;
        int r = e >> 8, c = e & 255;
        ushort8 d = *reinterpret_cast<const ushort8*>(A + (size_t)(m0 + r) * 256 + c);
        int byte = (r * 512 + c * 2) ^ ((r & 7) << 4);
        *reinterpret_cast<ushort8*>(reinterpret_cast<char*>(As) + byte) = d;
    }

    const int lane = tid & 63, wid = tid >> 6;
    const int wr = wid >> 1, wc = wid & 1;
    const int lr = lane & 15, lg = lane >> 4;

    for (int cb = 0; cb < 2; ++cb) {
        const int jbase = cb * 128;
        f32x4 acc[4][4];
        #pragma unroll
        for (int a = 0; a < 4; ++a)
            #pragma unroll
            for (int b = 0; b < 4; ++b) acc[a][b] = (f32x4){0.f, 0.f, 0.f, 0.f};

        for (int kk = 0; kk < 256; kk += 64) {
            __syncthreads();
            #pragma unroll
            for (int i = 0; i < 4; ++i) {
                int e = (i * 256 + tid) * 8;
                int r = e >> 6, c = e & 63;
                ushort8 d = *reinterpret_cast<const ushort8*>(WOT + (size_t)(jbase + r) * 256 + kk + c);
                int byte = (r * 128 + c * 2) ^ ((r & 7) << 4);
                *reinterpret_cast<ushort8*>(reinterpret_cast<char*>(Bs) + byte) = d;
            }
            __syncthreads();
            #pragma unroll
            for (int ks = 0; ks < 2; ++ks) {
                bf16x8 af[4], bfr[4];
                #pragma unroll
                for (int mt = 0; mt < 4; ++mt) {
                    int r = wr * 64 + mt * 16 + lr;
                    int byte = (r * 512 + (kk + ks * 32 + lg * 8) * 2) ^ ((r & 7) << 4);
                    af[mt] = *reinterpret_cast<const bf16x8*>(reinterpret_cast<const char*>(As) + byte);
                }
                #pragma unroll
                for (int nt = 0; nt < 4; ++nt) {
                    int r = wc * 64 + nt * 16 + lr;
                    int byte = (r * 128 + (ks * 32 + lg * 8) * 2) ^ ((r & 7) << 4);
                    bfr[nt] = *reinterpret_cast<const bf16x8*>(reinterpret_cast<const char*>(Bs) + byte);
                }
                #pragma unroll
                for (int mt = 0; mt < 4; ++mt)
                    #pragma unroll
                    for (int nt = 0; nt < 4; ++nt)
                        acc[mt][nt] = mfma16(af[mt], bfr[nt], acc[mt][nt]);
            }
        }
        float bcol[4];
        #pragma unroll
        for (int nt = 0; nt < 4; ++nt)
            bcol[nt] = bO[jbase + wc * 64 + nt * 16 + lr];
        #pragma unroll
        for (int mt = 0; mt < 4; ++mt) {
            #pragma unroll
            for (int nt = 0; nt < 4; ++nt) {
                #pragma unroll
                for (int j = 0; j < 4; ++j) {
                    float v = fmaxf(acc[mt][nt][j] + bcol[nt], 0.f);
                    int row = m0 + wr * 64 + mt * 16 + lg * 4 + j;
                    int col = jbase + wc * 64 + nt * 16 + lr;
                    Out[(size_t)row * 256 + col] = v;
                }
            }
        }
    }
}

// ---------------------------------------------------------------------------
extern "C" void kernel_launch(void* const* d_in, const int* in_sizes, int n_in,
                              void* d_out, int out_size, void* d_ws, size_t ws_size,
                              hipStream_t stream) {
    const float* x    = (const float*)d_in[0];
    const float* mask = (const float*)d_in[1];
    const float* Wv   = (const float*)d_in[2];
    const float* bv   = (const float*)d_in[3];
    const float* Wk   = (const float*)d_in[4];
    const float* bk   = (const float*)d_in[5];
    const float* Wq   = (const float*)d_in[6];
    const float* bq   = (const float*)d_in[7];
    const float* Wo   = (const float*)d_in[8];
    const float* bo   = (const float*)d_in[9];
    float* out = (float*)d_out;

    char* ws = (char*)d_ws;
    u16* WT  = (u16*)(ws);                          // 768*256 bf16 = 384KB
    u16* WOT = (u16*)(ws + 393216);                 // 256*256 bf16 = 128KB
    u16* Qb  = (u16*)(ws + 524288);                 // 33.55MB (also attn out)
    u16* Kb  = (u16*)(ws + 524288 + 33554432);      // 33.55MB
    u16* VTb = (u16*)(ws + 524288 + 2 * 33554432);  // 33.55MB, [b][h][n]

    prep_w<<<1024, 256, 0, stream>>>(Wq, Wk, Wv, Wo, WT, WOT);
    qkv_gemm<<<512, 256, 0, stream>>>(x, WT, bq, bk, bv, Qb, Kb, VTb);
    attn_kernel<<<512, 512, 0, stream>>>(Qb, Kb, VTb, mask, Qb);
    out_gemm<<<512, 256, 0, stream>>>(Qb, WOT, bo, out);
}